// Round 1
// baseline (1561.742 us; speedup 1.0000x reference)
//
#include <hip/hip_runtime.h>
#include <hip/hip_bf16.h>
#include <stdint.h>

typedef __hip_bfloat16 bf16;
typedef __attribute__((ext_vector_type(8))) short short8;
typedef __attribute__((ext_vector_type(4))) float f32x4;

#define M_DIM 8192
#define K_DIM 4096
#define N_DIM 16384
#define NELEM_W ((long)N_DIM * (long)K_DIM) /* 67108864 */
#define NELEM_X ((long)M_DIM * (long)K_DIM) /* 33554432 */

#define BM 128
#define BN 128
#define BK 32

// ---------------- helpers ----------------

__device__ __forceinline__ void g2l16(const void* g, void* l) {
  __builtin_amdgcn_global_load_lds(
      (const __attribute__((address_space(1))) unsigned int*)g,
      (__attribute__((address_space(3))) unsigned int*)l, 16, 0, 0);
}

// round-to-nearest-even f32 -> bf16 bits
__device__ __forceinline__ unsigned short f2bf(float f) {
  unsigned int u = __float_as_uint(f);
  u += 0x7FFFu + ((u >> 16) & 1u);
  return (unsigned short)(u >> 16);
}

// ---------------- scale = max(mean(|W|), 1e-8), deterministic fp64 ----------------

__global__ void reduce_absw(const float4* __restrict__ w4, double* __restrict__ partials, int n4) {
  const int tid = threadIdx.x;
  double s = 0.0;
  const int stride = gridDim.x * blockDim.x;
  for (int i = blockIdx.x * blockDim.x + tid; i < n4; i += stride) {
    float4 v = w4[i];
    s += (double)fabsf(v.x);
    s += (double)fabsf(v.y);
    s += (double)fabsf(v.z);
    s += (double)fabsf(v.w);
  }
  __shared__ double sd[256];
  sd[tid] = s;
  __syncthreads();
  for (int off = 128; off > 0; off >>= 1) {
    if (tid < off) sd[tid] += sd[tid + off];
    __syncthreads();
  }
  if (tid == 0) partials[blockIdx.x] = sd[0];
}

__global__ void finalize_scale(const double* __restrict__ partials, float* __restrict__ sp) {
  const int tid = threadIdx.x;
  double s = 0.0;
#pragma unroll
  for (int j = 0; j < 8; ++j) s += partials[tid * 8 + j];
  __shared__ double sd[256];
  sd[tid] = s;
  __syncthreads();
  for (int off = 128; off > 0; off >>= 1) {
    if (tid < off) sd[tid] += sd[tid + off];
    __syncthreads();
  }
  if (tid == 0) {
    double mean = sd[0] / (double)NELEM_W;
    float sc = (float)mean;
    if (sc < 1e-8f) sc = 1e-8f;
    sp[0] = sc;
  }
}

// ---------------- quantize W -> ternary bf16 {-1,0,+1}; convert x -> bf16 ----------------

__global__ void quant_w(const float4* __restrict__ w4, ushort4* __restrict__ q4,
                        const float* __restrict__ sp, int n4) {
  const float sc = sp[0];
  const int stride = gridDim.x * blockDim.x;
  for (int i = blockIdx.x * blockDim.x + threadIdx.x; i < n4; i += stride) {
    float4 v = w4[i];
    ushort4 o;
    o.x = f2bf(rintf(fminf(fmaxf(v.x / sc, -1.f), 1.f)));
    o.y = f2bf(rintf(fminf(fmaxf(v.y / sc, -1.f), 1.f)));
    o.z = f2bf(rintf(fminf(fmaxf(v.z / sc, -1.f), 1.f)));
    o.w = f2bf(rintf(fminf(fmaxf(v.w / sc, -1.f), 1.f)));
    q4[i] = o;
  }
}

__global__ void cvt_x(const float4* __restrict__ x4, ushort4* __restrict__ o4, int n4) {
  const int stride = gridDim.x * blockDim.x;
  for (int i = blockIdx.x * blockDim.x + threadIdx.x; i < n4; i += stride) {
    float4 v = x4[i];
    ushort4 o;
    o.x = f2bf(v.x);
    o.y = f2bf(v.y);
    o.z = f2bf(v.z);
    o.w = f2bf(v.w);
    o4[i] = o;
  }
}

// ---------------- main GEMM: C[M,N] = Xb[M,K] * Wq[N,K]^T, epilogue * scale ----------------
// m97 structure: 128x128 tile, BK=32, 4 waves (2x2), global_load_lds width=16,
// 16 MFMA 16x16x32 bf16 per K-step per wave, 2 barriers per K-step.

__global__ __launch_bounds__(256)
void gemm_bf16(const bf16* __restrict__ A, const bf16* __restrict__ B,
               float* __restrict__ C, const float* __restrict__ sp) {
  __shared__ alignas(16) bf16 As[BM * BK]; // 8 KB, linear [row*32 + k]
  __shared__ alignas(16) bf16 Bs[BN * BK]; // 8 KB

  const int tid = threadIdx.x;
  const int wave = tid >> 6;
  const int lane = tid & 63;

  // bijective XCD swizzle (nwg = 8192, divisible by 8)
  int wgid = blockIdx.x;
  wgid = (wgid & 7) * (gridDim.x >> 3) + (wgid >> 3);
  const int nbn = N_DIM / BN; // 128
  const int bm = wgid / nbn;
  const int bn = wgid % nbn;

  // staging: thread t loads 16B; row = t/4, col8 = (t%4)*8 elements
  const int srow = tid >> 2;
  const int scol = (tid & 3) * 8;
  const bf16* Ag0 = A + (long)(bm * BM + srow) * K_DIM + scol;
  const bf16* Ag1 = Ag0 + (long)64 * K_DIM;
  const bf16* Bg0 = B + (long)(bn * BN + srow) * K_DIM + scol;
  const bf16* Bg1 = Bg0 + (long)64 * K_DIM;

  bf16* lA0 = As + tid * 8;         // byte tid*16 = wave*1024 + lane*16 (wave-uniform base + lane*16)
  bf16* lA1 = As + 2048 + tid * 8;
  bf16* lB0 = Bs + tid * 8;
  bf16* lB1 = Bs + 2048 + tid * 8;

  // wave -> 64x64 output subtile
  const int wr = (wave >> 1) * 64;
  const int wc = (wave & 1) * 64;
  const int fr = lane & 15; // frag row (A) / col (B,C)
  const int fq = lane >> 4; // k-group 0..3

  const char* AsB = (const char*)As;
  const char* BsB = (const char*)Bs;
  const unsigned aoff = (unsigned)((wr + fr) * 64 + fq * 16); // bytes
  const unsigned boff = (unsigned)((wc + fr) * 64 + fq * 16);

  f32x4 acc[4][4] = {};

  for (int kt = 0; kt < K_DIM; kt += BK) {
    g2l16(Ag0 + kt, lA0);
    g2l16(Ag1 + kt, lA1);
    g2l16(Bg0 + kt, lB0);
    g2l16(Bg1 + kt, lB1);
    __syncthreads(); // drains vmcnt -> LDS tiles valid

    short8 a[4], b[4];
#pragma unroll
    for (int m = 0; m < 4; ++m)
      a[m] = *(const short8*)(AsB + aoff + m * (16 * 64));
#pragma unroll
    for (int n = 0; n < 4; ++n)
      b[n] = *(const short8*)(BsB + boff + n * (16 * 64));
#pragma unroll
    for (int m = 0; m < 4; ++m)
#pragma unroll
      for (int n = 0; n < 4; ++n)
        acc[m][n] = __builtin_amdgcn_mfma_f32_16x16x32_bf16(a[m], b[n], acc[m][n], 0, 0, 0);

    __syncthreads(); // protect LDS from next-iteration staging
  }

  // epilogue: C/D layout col = lane&15, row = (lane>>4)*4 + reg
  const float s = sp[0];
  const long crow0 = (long)(bm * BM + wr + fq * 4);
  const int ccol0 = bn * BN + wc + fr;
#pragma unroll
  for (int m = 0; m < 4; ++m) {
#pragma unroll
    for (int n = 0; n < 4; ++n) {
#pragma unroll
      for (int j = 0; j < 4; ++j) {
        long row = crow0 + (long)(m * 16 + j);
        int col = ccol0 + n * 16;
        C[row * N_DIM + col] = acc[m][n][j] * s;
      }
    }
  }
}

// ---------------- fallback (ws too small): quantize/convert on the fly ----------------

__global__ __launch_bounds__(256)
void gemm_fly(const float* __restrict__ X, const float* __restrict__ W,
              float* __restrict__ C, const float* __restrict__ sp) {
  __shared__ alignas(16) bf16 As[BM * BK];
  __shared__ alignas(16) bf16 Bs[BN * BK];

  const int tid = threadIdx.x;
  const int wave = tid >> 6;
  const int lane = tid & 63;

  int wgid = blockIdx.x;
  wgid = (wgid & 7) * (gridDim.x >> 3) + (wgid >> 3);
  const int nbn = N_DIM / BN;
  const int bm = wgid / nbn;
  const int bn = wgid % nbn;

  const float sc = sp[0];

  const int wr = (wave >> 1) * 64;
  const int wc = (wave & 1) * 64;
  const int fr = lane & 15;
  const int fq = lane >> 4;
  const char* AsB = (const char*)As;
  const char* BsB = (const char*)Bs;
  const unsigned aoff = (unsigned)((wr + fr) * 64 + fq * 16);
  const unsigned boff = (unsigned)((wc + fr) * 64 + fq * 16);

  f32x4 acc[4][4] = {};

  for (int kt = 0; kt < K_DIM; kt += BK) {
#pragma unroll
    for (int r = 0; r < 4; ++r) {
      int e = r * 1024 + tid * 4;
      int row = e >> 5;
      int k4 = e & 31;
      float4 xv = *(const float4*)(X + (long)(bm * BM + row) * K_DIM + kt + k4);
      ushort4 xb;
      xb.x = f2bf(xv.x); xb.y = f2bf(xv.y); xb.z = f2bf(xv.z); xb.w = f2bf(xv.w);
      *(ushort4*)(As + e) = xb;
      float4 wv = *(const float4*)(W + (long)(bn * BN + row) * K_DIM + kt + k4);
      ushort4 wb;
      wb.x = f2bf(rintf(fminf(fmaxf(wv.x / sc, -1.f), 1.f)));
      wb.y = f2bf(rintf(fminf(fmaxf(wv.y / sc, -1.f), 1.f)));
      wb.z = f2bf(rintf(fminf(fmaxf(wv.z / sc, -1.f), 1.f)));
      wb.w = f2bf(rintf(fminf(fmaxf(wv.w / sc, -1.f), 1.f)));
      *(ushort4*)(Bs + e) = wb;
    }
    __syncthreads();

    short8 a[4], b[4];
#pragma unroll
    for (int m = 0; m < 4; ++m)
      a[m] = *(const short8*)(AsB + aoff + m * (16 * 64));
#pragma unroll
    for (int n = 0; n < 4; ++n)
      b[n] = *(const short8*)(BsB + boff + n * (16 * 64));
#pragma unroll
    for (int m = 0; m < 4; ++m)
#pragma unroll
      for (int n = 0; n < 4; ++n)
        acc[m][n] = __builtin_amdgcn_mfma_f32_16x16x32_bf16(a[m], b[n], acc[m][n], 0, 0, 0);

    __syncthreads();
  }

  const long crow0 = (long)(bm * BM + wr + fq * 4);
  const int ccol0 = bn * BN + wc + fr;
#pragma unroll
  for (int m = 0; m < 4; ++m)
#pragma unroll
    for (int n = 0; n < 4; ++n)
#pragma unroll
      for (int j = 0; j < 4; ++j) {
        long row = crow0 + (long)(m * 16 + j);
        int col = ccol0 + n * 16;
        C[row * N_DIM + col] = acc[m][n][j] * sc;
      }
}

// ---------------- launch ----------------

extern "C" void kernel_launch(void* const* d_in, const int* in_sizes, int n_in,
                              void* d_out, int out_size, void* d_ws, size_t ws_size,
                              hipStream_t stream) {
  const float* x = (const float*)d_in[0];
  const float* w = (const float*)d_in[1];
  float* out = (float*)d_out;

  char* ws = (char*)d_ws;
  double* partials = (double*)ws;          // 2048 doubles = 16 KB
  float* sp = (float*)(ws + 16384);        // scale
  const size_t WQ_OFF = 32768;
  const size_t XB_OFF = WQ_OFF + (size_t)NELEM_W * 2;
  const size_t NEEDED = XB_OFF + (size_t)NELEM_X * 2;

  reduce_absw<<<2048, 256, 0, stream>>>((const float4*)w, partials, (int)(NELEM_W / 4));
  finalize_scale<<<1, 256, 0, stream>>>(partials, sp);

  const int grid = (M_DIM / BM) * (N_DIM / BN); // 8192

  if (ws_size >= NEEDED) {
    bf16* wq = (bf16*)(ws + WQ_OFF);
    bf16* xb = (bf16*)(ws + XB_OFF);
    quant_w<<<2048, 256, 0, stream>>>((const float4*)w, (ushort4*)wq, sp, (int)(NELEM_W / 4));
    cvt_x<<<2048, 256, 0, stream>>>((const float4*)x, (ushort4*)xb, (int)(NELEM_X / 4));
    gemm_bf16<<<grid, 256, 0, stream>>>(xb, wq, out, sp);
  } else {
    gemm_fly<<<grid, 256, 0, stream>>>(x, w, out, sp);
  }
}

// Round 3
// 1173.009 us; speedup vs baseline: 1.3314x; 1.3314x over previous
//
#include <hip/hip_runtime.h>
#include <hip/hip_bf16.h>
#include <stdint.h>

typedef __hip_bfloat16 bf16;
typedef __attribute__((ext_vector_type(8))) short short8;
typedef __attribute__((ext_vector_type(4))) float f32x4;

#define M_DIM 8192
#define K_DIM 4096
#define N_DIM 16384
#define NELEM_W ((long)N_DIM * (long)K_DIM) /* 67108864 */
#define NELEM_X ((long)M_DIM * (long)K_DIM) /* 33554432 */

// ---------------- helpers ----------------

__device__ __forceinline__ void g2l16(const void* g, void* l) {
  __builtin_amdgcn_global_load_lds(
      (const __attribute__((address_space(1))) unsigned int*)g,
      (__attribute__((address_space(3))) unsigned int*)l, 16, 0, 0);
}

// round-to-nearest-even f32 -> bf16 bits
__device__ __forceinline__ unsigned short f2bf(float f) {
  unsigned int u = __float_as_uint(f);
  u += 0x7FFFu + ((u >> 16) & 1u);
  return (unsigned short)(u >> 16);
}

// ---------------- scale = max(mean(|W|), 1e-8), deterministic fp64 ----------------

__global__ void reduce_absw(const float4* __restrict__ w4, double* __restrict__ partials, int n4) {
  const int tid = threadIdx.x;
  double s = 0.0;
  const int stride = gridDim.x * blockDim.x;
  for (int i = blockIdx.x * blockDim.x + tid; i < n4; i += stride) {
    float4 v = w4[i];
    s += (double)fabsf(v.x);
    s += (double)fabsf(v.y);
    s += (double)fabsf(v.z);
    s += (double)fabsf(v.w);
  }
  __shared__ double sd[256];
  sd[tid] = s;
  __syncthreads();
  for (int off = 128; off > 0; off >>= 1) {
    if (tid < off) sd[tid] += sd[tid + off];
    __syncthreads();
  }
  if (tid == 0) partials[blockIdx.x] = sd[0];
}

__global__ void finalize_scale(const double* __restrict__ partials, float* __restrict__ sp) {
  const int tid = threadIdx.x;
  double s = 0.0;
#pragma unroll
  for (int j = 0; j < 8; ++j) s += partials[tid * 8 + j];
  __shared__ double sd[256];
  sd[tid] = s;
  __syncthreads();
  for (int off = 128; off > 0; off >>= 1) {
    if (tid < off) sd[tid] += sd[tid + off];
    __syncthreads();
  }
  if (tid == 0) {
    double mean = sd[0] / (double)NELEM_W;
    float sc = (float)mean;
    if (sc < 1e-8f) sc = 1e-8f;
    sp[0] = sc;
  }
}

// ---------------- quantize W -> ternary bf16 {-1,0,+1}; convert x -> bf16 ----------------

__global__ void quant_w(const float4* __restrict__ w4, ushort4* __restrict__ q4,
                        const float* __restrict__ sp, int n4) {
  const float sc = sp[0];
  const int stride = gridDim.x * blockDim.x;
  for (int i = blockIdx.x * blockDim.x + threadIdx.x; i < n4; i += stride) {
    float4 v = w4[i];
    ushort4 o;
    o.x = f2bf(rintf(fminf(fmaxf(v.x / sc, -1.f), 1.f)));
    o.y = f2bf(rintf(fminf(fmaxf(v.y / sc, -1.f), 1.f)));
    o.z = f2bf(rintf(fminf(fmaxf(v.z / sc, -1.f), 1.f)));
    o.w = f2bf(rintf(fminf(fmaxf(v.w / sc, -1.f), 1.f)));
    q4[i] = o;
  }
}

__global__ void cvt_x(const float4* __restrict__ x4, ushort4* __restrict__ o4, int n4) {
  const int stride = gridDim.x * blockDim.x;
  for (int i = blockIdx.x * blockDim.x + threadIdx.x; i < n4; i += stride) {
    float4 v = x4[i];
    ushort4 o;
    o.x = f2bf(v.x);
    o.y = f2bf(v.y);
    o.z = f2bf(v.z);
    o.w = f2bf(v.w);
    o4[i] = o;
  }
}

// ---------------- 256x256 8-phase GEMM: C[M,N] = Xb[M,K] * Wq[N,K]^T ----------------
// BM=BN=256, BK=64, 8 waves (2Mx4N), 128 KiB LDS (2 dbuf x (A 32K + B 32K)).
// Half-tile = 128 rows x 64 cols bf16 = 16 KB, staged by 2 global_load_lds/thread.
// XOR swizzle: physical 16B slot = logical slot ^ (row&7) (inverse-swizzled global
// source + linear LDS dest + swizzled ds_read -- rule 21 both-sides).
// vmcnt ledger (per wave, 2 loads per STG):
//   prologue: issue 10, vmcnt(2) -> buf0 landed, A0(t1) in flight
//   steady:   P1..P3 +2 each, P4 +2 then vmcnt(2) -> drains exactly t1's 8, leaves A0(t2)
//   tail (no staging left): vmcnt(0)  <- round-2 bug was vmcnt(2) here, leaving
//   B1(kt=63) in flight while P5 read it (absmax 42 == 5.6 sigma of one stale K-tile).

template<int MH, int NH>
__device__ __forceinline__ void mfmaq(f32x4 (&acc)[8][4], const short8 (&a)[8], const short8 (&bfr)[8]) {
#pragma unroll
  for (int im = 0; im < 4; ++im) {
#pragma unroll
    for (int in = 0; in < 2; ++in) {
      const int m = MH * 4 + im, n = NH * 2 + in;
      acc[m][n] = __builtin_amdgcn_mfma_f32_16x16x32_bf16(a[im * 2 + 0], bfr[n * 2 + 0], acc[m][n], 0, 0, 0);
      acc[m][n] = __builtin_amdgcn_mfma_f32_16x16x32_bf16(a[im * 2 + 1], bfr[n * 2 + 1], acc[m][n], 0, 0, 0);
    }
  }
}

#define FENCE asm volatile("" ::: "memory")
#define BAR do { FENCE; __builtin_amdgcn_s_barrier(); FENCE; } while (0)
#define VMW2 asm volatile("s_waitcnt vmcnt(2)" ::: "memory")
#define VMW0 asm volatile("s_waitcnt vmcnt(0)" ::: "memory")

// stage half-tile h of operand into buffer bb at K-tile kt (2 x global_load_lds 16B)
#define STG_A(bb, h, kt) do { \
    const char* g_ = Ac + aG + (unsigned)(h) * 1048576u + (unsigned)(kt) * 128u; \
    char* l_ = lds + (unsigned)(bb) * 32768u + (unsigned)(h) * 16384u + ldsT; \
    g2l16(g_, l_); g2l16(g_ + 524288u, l_ + 8192u); \
  } while (0)
#define STG_B(bb, h, kt) do { \
    const char* g_ = Bc + bG + (unsigned)(h) * 1048576u + (unsigned)(kt) * 128u; \
    char* l_ = lds + 65536u + (unsigned)(bb) * 32768u + (unsigned)(h) * 16384u + ldsT; \
    g2l16(g_, l_); g2l16(g_ + 524288u, l_ + 8192u); \
  } while (0)

#define LDA_(d, bb, m, ks) d = *(const short8*)(lds + Abase##bb + (unsigned)(m) * 2048u + frk + coff##ks)
#define LDB_(d, bb, n, ks) d = *(const short8*)(lds + Bbase##bb + (unsigned)(n) * 2048u + frk + coff##ks)

__global__ __launch_bounds__(512, 2)
void gemm256(const bf16* __restrict__ A, const bf16* __restrict__ B,
             float* __restrict__ C, const float* __restrict__ sp) {
  extern __shared__ char lds[];

  const int tid = threadIdx.x;
  const int wave = tid >> 6, lane = tid & 63;
  const int fr = lane & 15, fq = lane >> 4;
  const int wr = wave >> 2;        // 0..1 (M)
  const int wc = wave & 3;         // 0..3 (N)

  // bijective XCD swizzle (2048 % 8 == 0)
  int wgid = blockIdx.x;
  wgid = (wgid & 7) * ((int)gridDim.x >> 3) + (wgid >> 3);
  const int bm = wgid >> 6;        // N/256 = 64 tile-cols
  const int bn = wgid & 63;

  // ---- staging addressing: thread -> (row r0, physical slot pslot) of a half-tile
  const int r0 = tid >> 3;                  // 0..63 (second load adds +64 rows)
  const int pslot = tid & 7;
  const int lslot = pslot ^ (r0 & 7);       // inverse-swizzled source slot
  const unsigned aG = ((unsigned)(bm * 256 + r0) * K_DIM + (unsigned)lslot * 8u) * 2u;
  const unsigned bG = ((unsigned)(bn * 256 + r0) * K_DIM + (unsigned)lslot * 8u) * 2u;
  const unsigned ldsT = (unsigned)tid * 16u;
  const char* Ac = (const char*)A;
  const char* Bc = (const char*)B;

  // ---- fragment read addressing (swizzled)
  const unsigned axor = (unsigned)(fr & 7) << 4;
  const unsigned coff0 = ((unsigned)(fq * 16)) ^ axor;        // ks=0 (k 0..31)
  const unsigned coff1 = ((unsigned)(64 + fq * 16)) ^ axor;   // ks=1 (k 32..63)
  const unsigned frk = (unsigned)fr * 128u;
  const unsigned Abase0 = (unsigned)(wr * 16384);
  const unsigned Abase1 = (unsigned)(32768 + wr * 16384);
  const unsigned Bhalf = (unsigned)(65536 + (wc >> 1) * 16384 + (wc & 1) * 8192);
  const unsigned Bbase0 = Bhalf;
  const unsigned Bbase1 = Bhalf + 32768u;

  f32x4 acc[8][4] = {};
  short8 a[8], bfr[8];

  // ---- prologue: kt0 -> buf0 (4 half-tiles), kt1 A-half0 -> buf1
  STG_A(0, 0, 0); STG_A(0, 1, 0);
  STG_B(0, 0, 0); STG_B(0, 1, 0);
  STG_A(1, 0, 1);
  VMW2;      // kt0 fully landed; kt1-A0 in flight
  BAR;

#pragma unroll 1
  for (int i = 0; i < 32; ++i) {
    const int t1 = 2 * i + 1, t2 = 2 * i + 2, t3 = 2 * i + 3;

    // ---- P1: buf0 quadrant (0,0); read A[0-3],B[0-1]; stage A-h1 of t1 -> buf1
#pragma unroll
    for (int im = 0; im < 4; ++im) { LDA_(a[im * 2 + 0], 0, im, 0); LDA_(a[im * 2 + 1], 0, im, 1); }
#pragma unroll
    for (int n = 0; n < 2; ++n) { LDB_(bfr[n * 2 + 0], 0, n, 0); LDB_(bfr[n * 2 + 1], 0, n, 1); }
    STG_A(1, 1, t1);
    BAR;
    __builtin_amdgcn_s_setprio(1); mfmaq<0, 0>(acc, a, bfr); __builtin_amdgcn_s_setprio(0);
    BAR;

    // ---- P2: quadrant (0,1); read B[2-3]; stage B-h0 of t1 -> buf1
#pragma unroll
    for (int n = 2; n < 4; ++n) { LDB_(bfr[n * 2 + 0], 0, n, 0); LDB_(bfr[n * 2 + 1], 0, n, 1); }
    STG_B(1, 0, t1);
    BAR;
    __builtin_amdgcn_s_setprio(1); mfmaq<0, 1>(acc, a, bfr); __builtin_amdgcn_s_setprio(0);
    BAR;

    // ---- P3: quadrant (1,1); read A[4-7]; stage B-h1 of t1 -> buf1
#pragma unroll
    for (int im = 0; im < 4; ++im) { LDA_(a[im * 2 + 0], 0, im + 4, 0); LDA_(a[im * 2 + 1], 0, im + 4, 1); }
    STG_B(1, 1, t1);
    BAR;
    __builtin_amdgcn_s_setprio(1); mfmaq<1, 1>(acc, a, bfr); __builtin_amdgcn_s_setprio(0);
    BAR;

    // ---- P4: quadrant (1,0); stage A-h0 of t2 -> buf0; drain t1
    if (t2 < 64) { STG_A(0, 0, t2); VMW2; } else { VMW0; }
    BAR;
    __builtin_amdgcn_s_setprio(1); mfmaq<1, 0>(acc, a, bfr); __builtin_amdgcn_s_setprio(0);
    BAR;

    // ---- P5: buf1 quadrant (0,0); read A[0-3],B[0-1]; stage A-h1 of t2 -> buf0
#pragma unroll
    for (int im = 0; im < 4; ++im) { LDA_(a[im * 2 + 0], 1, im, 0); LDA_(a[im * 2 + 1], 1, im, 1); }
#pragma unroll
    for (int n = 0; n < 2; ++n) { LDB_(bfr[n * 2 + 0], 1, n, 0); LDB_(bfr[n * 2 + 1], 1, n, 1); }
    if (t2 < 64) STG_A(0, 1, t2);
    BAR;
    __builtin_amdgcn_s_setprio(1); mfmaq<0, 0>(acc, a, bfr); __builtin_amdgcn_s_setprio(0);
    BAR;

    // ---- P6: quadrant (0,1); read B[2-3]; stage B-h0 of t2 -> buf0
#pragma unroll
    for (int n = 2; n < 4; ++n) { LDB_(bfr[n * 2 + 0], 1, n, 0); LDB_(bfr[n * 2 + 1], 1, n, 1); }
    if (t2 < 64) STG_B(0, 0, t2);
    BAR;
    __builtin_amdgcn_s_setprio(1); mfmaq<0, 1>(acc, a, bfr); __builtin_amdgcn_s_setprio(0);
    BAR;

    // ---- P7: quadrant (1,1); read A[4-7]; stage B-h1 of t2 -> buf0
#pragma unroll
    for (int im = 0; im < 4; ++im) { LDA_(a[im * 2 + 0], 1, im + 4, 0); LDA_(a[im * 2 + 1], 1, im + 4, 1); }
    if (t2 < 64) STG_B(0, 1, t2);
    BAR;
    __builtin_amdgcn_s_setprio(1); mfmaq<1, 1>(acc, a, bfr); __builtin_amdgcn_s_setprio(0);
    BAR;

    // ---- P8: quadrant (1,0); stage A-h0 of t3 -> buf1; drain t2
    if (t3 < 64) { STG_A(1, 0, t3); VMW2; } else { VMW0; }
    BAR;
    __builtin_amdgcn_s_setprio(1); mfmaq<1, 0>(acc, a, bfr); __builtin_amdgcn_s_setprio(0);
    BAR;
  }

  // ---- epilogue: C/D layout col = lane&15 (fr), row = fq*4 + j
  const float s = sp[0];
  const int crow0 = bm * 256 + wr * 128 + fq * 4;
  const int ccol0 = bn * 256 + wc * 64 + fr;
#pragma unroll
  for (int m = 0; m < 8; ++m) {
#pragma unroll
    for (int n = 0; n < 4; ++n) {
#pragma unroll
      for (int j = 0; j < 4; ++j) {
        C[(long)(crow0 + m * 16 + j) * N_DIM + (ccol0 + n * 16)] = acc[m][n][j] * s;
      }
    }
  }
}

// ---------------- fallback (ws too small): quantize/convert on the fly, 128^2 ----------------

__global__ __launch_bounds__(256)
void gemm_fly(const float* __restrict__ X, const float* __restrict__ W,
              float* __restrict__ C, const float* __restrict__ sp) {
  __shared__ alignas(16) bf16 As[128 * 32];
  __shared__ alignas(16) bf16 Bs[128 * 32];

  const int tid = threadIdx.x;
  const int wave = tid >> 6;
  const int lane = tid & 63;

  int wgid = blockIdx.x;
  wgid = (wgid & 7) * ((int)gridDim.x >> 3) + (wgid >> 3);
  const int nbn = N_DIM / 128;
  const int bm = wgid / nbn;
  const int bn = wgid % nbn;

  const float sc = sp[0];

  const int wr = (wave >> 1) * 64;
  const int wc = (wave & 1) * 64;
  const int fr = lane & 15;
  const int fq = lane >> 4;
  const char* AsB = (const char*)As;
  const char* BsB = (const char*)Bs;
  const unsigned aoff = (unsigned)((wr + fr) * 64 + fq * 16);
  const unsigned boff = (unsigned)((wc + fr) * 64 + fq * 16);

  f32x4 acc[4][4] = {};

  for (int kt = 0; kt < K_DIM; kt += 32) {
#pragma unroll
    for (int r = 0; r < 4; ++r) {
      int e = r * 1024 + tid * 4;
      int row = e >> 5;
      int k4 = e & 31;
      float4 xv = *(const float4*)(X + (long)(bm * 128 + row) * K_DIM + kt + k4);
      ushort4 xb;
      xb.x = f2bf(xv.x); xb.y = f2bf(xv.y); xb.z = f2bf(xv.z); xb.w = f2bf(xv.w);
      *(ushort4*)(As + e) = xb;
      float4 wv = *(const float4*)(W + (long)(bn * 128 + row) * K_DIM + kt + k4);
      ushort4 wb;
      wb.x = f2bf(rintf(fminf(fmaxf(wv.x / sc, -1.f), 1.f)));
      wb.y = f2bf(rintf(fminf(fmaxf(wv.y / sc, -1.f), 1.f)));
      wb.z = f2bf(rintf(fminf(fmaxf(wv.z / sc, -1.f), 1.f)));
      wb.w = f2bf(rintf(fminf(fmaxf(wv.w / sc, -1.f), 1.f)));
      *(ushort4*)(Bs + e) = wb;
    }
    __syncthreads();

    short8 a[4], b[4];
#pragma unroll
    for (int m = 0; m < 4; ++m)
      a[m] = *(const short8*)(AsB + aoff + m * (16 * 64));
#pragma unroll
    for (int n = 0; n < 4; ++n)
      b[n] = *(const short8*)(BsB + boff + n * (16 * 64));
#pragma unroll
    for (int m = 0; m < 4; ++m)
#pragma unroll
      for (int n = 0; n < 4; ++n)
        acc[m][n] = __builtin_amdgcn_mfma_f32_16x16x32_bf16(a[m], b[n], acc[m][n], 0, 0, 0);

    __syncthreads();
  }

  const long crow0 = (long)(bm * 128 + wr + fq * 4);
  const int ccol0 = bn * 128 + wc + fr;
#pragma unroll
  for (int m = 0; m < 4; ++m)
#pragma unroll
    for (int n = 0; n < 4; ++n)
#pragma unroll
      for (int j = 0; j < 4; ++j) {
        long row = crow0 + (long)(m * 16 + j);
        int col = ccol0 + n * 16;
        C[row * N_DIM + col] = acc[m][n][j] * sc;
      }
}

// ---------------- launch ----------------

extern "C" void kernel_launch(void* const* d_in, const int* in_sizes, int n_in,
                              void* d_out, int out_size, void* d_ws, size_t ws_size,
                              hipStream_t stream) {
  const float* x = (const float*)d_in[0];
  const float* w = (const float*)d_in[1];
  float* out = (float*)d_out;

  char* ws = (char*)d_ws;
  double* partials = (double*)ws;          // 2048 doubles = 16 KB
  float* sp = (float*)(ws + 16384);        // scale
  const size_t WQ_OFF = 32768;
  const size_t XB_OFF = WQ_OFF + (size_t)NELEM_W * 2;
  const size_t NEEDED = XB_OFF + (size_t)NELEM_X * 2;

  reduce_absw<<<2048, 256, 0, stream>>>((const float4*)w, partials, (int)(NELEM_W / 4));
  finalize_scale<<<1, 256, 0, stream>>>(partials, sp);

  if (ws_size >= NEEDED) {
    bf16* wq = (bf16*)(ws + WQ_OFF);
    bf16* xb = (bf16*)(ws + XB_OFF);
    quant_w<<<2048, 256, 0, stream>>>((const float4*)w, (ushort4*)wq, sp, (int)(NELEM_W / 4));
    cvt_x<<<2048, 256, 0, stream>>>((const float4*)x, (ushort4*)xb, (int)(NELEM_X / 4));

    static const int lds_bytes = 131072;
    (void)hipFuncSetAttribute((const void*)gemm256,
                              hipFuncAttributeMaxDynamicSharedMemorySize, lds_bytes);
    const int grid = (M_DIM / 256) * (N_DIM / 256); // 32 * 64 = 2048
    gemm256<<<grid, 512, lds_bytes, stream>>>(xb, wq, out, sp);
  } else {
    const int grid = (M_DIM / 128) * (N_DIM / 128);
    gemm_fly<<<grid, 256, 0, stream>>>(x, w, out, sp);
  }
}

// Round 4
// 1057.973 us; speedup vs baseline: 1.4762x; 1.1087x over previous
//
#include <hip/hip_runtime.h>
#include <hip/hip_bf16.h>
#include <stdint.h>

typedef __hip_bfloat16 bf16;
typedef __attribute__((ext_vector_type(8))) short short8;
typedef __attribute__((ext_vector_type(4))) float f32x4;

#define M_DIM 8192
#define K_DIM 4096
#define N_DIM 16384
#define NELEM_W ((long)N_DIM * (long)K_DIM) /* 67108864 */
#define NELEM_X ((long)M_DIM * (long)K_DIM) /* 33554432 */

// ---------------- helpers ----------------

__device__ __forceinline__ void g2l16(const void* g, void* l) {
  __builtin_amdgcn_global_load_lds(
      (const __attribute__((address_space(1))) unsigned int*)g,
      (__attribute__((address_space(3))) unsigned int*)l, 16, 0, 0);
}

// round-to-nearest-even f32 -> bf16 bits
__device__ __forceinline__ unsigned short f2bf(float f) {
  unsigned int u = __float_as_uint(f);
  u += 0x7FFFu + ((u >> 16) & 1u);
  return (unsigned short)(u >> 16);
}

// ---------------- scale = max(mean(|W|), 1e-8), deterministic fp64 ----------------

__global__ void reduce_absw(const float4* __restrict__ w4, double* __restrict__ partials, int n4) {
  const int tid = threadIdx.x;
  double s = 0.0;
  const int stride = gridDim.x * blockDim.x;
  for (int i = blockIdx.x * blockDim.x + tid; i < n4; i += stride) {
    float4 v = w4[i];
    s += (double)fabsf(v.x);
    s += (double)fabsf(v.y);
    s += (double)fabsf(v.z);
    s += (double)fabsf(v.w);
  }
  __shared__ double sd[256];
  sd[tid] = s;
  __syncthreads();
  for (int off = 128; off > 0; off >>= 1) {
    if (tid < off) sd[tid] += sd[tid + off];
    __syncthreads();
  }
  if (tid == 0) partials[blockIdx.x] = sd[0];
}

__global__ void finalize_scale(const double* __restrict__ partials, float* __restrict__ sp) {
  const int tid = threadIdx.x;
  double s = 0.0;
#pragma unroll
  for (int j = 0; j < 8; ++j) s += partials[tid * 8 + j];
  __shared__ double sd[256];
  sd[tid] = s;
  __syncthreads();
  for (int off = 128; off > 0; off >>= 1) {
    if (tid < off) sd[tid] += sd[tid + off];
    __syncthreads();
  }
  if (tid == 0) {
    double mean = sd[0] / (double)NELEM_W;
    float sc = (float)mean;
    if (sc < 1e-8f) sc = 1e-8f;
    sp[0] = sc;
  }
}

// ---------------- quantize W -> ternary bf16 {-1,0,+1}; convert x -> bf16 ----------------

__global__ void quant_w(const float4* __restrict__ w4, ushort4* __restrict__ q4,
                        const float* __restrict__ sp, int n4) {
  const float sc = sp[0];
  const int stride = gridDim.x * blockDim.x;
  for (int i = blockIdx.x * blockDim.x + threadIdx.x; i < n4; i += stride) {
    float4 v = w4[i];
    ushort4 o;
    o.x = f2bf(rintf(fminf(fmaxf(v.x / sc, -1.f), 1.f)));
    o.y = f2bf(rintf(fminf(fmaxf(v.y / sc, -1.f), 1.f)));
    o.z = f2bf(rintf(fminf(fmaxf(v.z / sc, -1.f), 1.f)));
    o.w = f2bf(rintf(fminf(fmaxf(v.w / sc, -1.f), 1.f)));
    q4[i] = o;
  }
}

__global__ void cvt_x(const float4* __restrict__ x4, ushort4* __restrict__ o4, int n4) {
  const int stride = gridDim.x * blockDim.x;
  for (int i = blockIdx.x * blockDim.x + threadIdx.x; i < n4; i += stride) {
    float4 v = x4[i];
    ushort4 o;
    o.x = f2bf(v.x);
    o.y = f2bf(v.y);
    o.z = f2bf(v.z);
    o.w = f2bf(v.w);
    o4[i] = o;
  }
}

// ---------------- 256x256 8-phase GEMM: C[M,N] = Xb[M,K] * Wq[N,K]^T ----------------
// BM=BN=256, BK=64, 8 waves (2Mx4N), 128 KiB LDS (2 dbuf x (A 32K + B 32K)).
// DEEP vmcnt LEDGER (r4): 3 half-tiles in flight, vmcnt(6) at P4/P8 only.
//   Reads: P1/P5 = a(A frags 0-3) + ALL B (16 ds_read_b128); P3/P7 = a(A frags 4-7).
//   => B-buf free after P1, A-buf free after P3 (region-freedom for staging).
//   Staging (iter i, t=2i consumed P1-P4 from buf0, t+1 P5-P8 from buf1):
//     P1:(t+1).A1->buf1  P2:(t+2).B0->buf0  P3:(t+2).B1  P4:(t+2).A0 +vmcnt(6)
//     P5:(t+2).A1        P6:(t+3).B0->buf1  P7:(t+3).B1  P8:(t+3).A0 +vmcnt(6)
//   Drain@P4: queue=[t1B0@-P6,t1B1@-P7,t1A0@-P8,t1A1@P1,t2B0,t2B1,t2A0]=14;
//             vmcnt(6) drains exactly t+1's 8; youngest drained is 3 phases old.
//   Drain@P8: symmetric; drains t+2's 8, youngest (A1@P5) 3 phases old.
//   Region check: t2.B0@P2 overwrites B-buf0 (read P1, done); t2.A0@P4 overwrites
//   A-buf0 (read P1+P3, done). Prologue: t0 x4 + t1.{B0,B1,A0} = 14 loads, vmcnt(6)
//   lands t0. Tail (i=31) peeled: P1 stages t63.A1, P4 drains vmcnt(0).

template<int MH, int NH>
__device__ __forceinline__ void mfmaq(f32x4 (&acc)[8][4], const short8 (&a)[8], const short8 (&bfr)[8]) {
#pragma unroll
  for (int im = 0; im < 4; ++im) {
#pragma unroll
    for (int in = 0; in < 2; ++in) {
      const int m = MH * 4 + im, n = NH * 2 + in;
      acc[m][n] = __builtin_amdgcn_mfma_f32_16x16x32_bf16(a[im * 2 + 0], bfr[n * 2 + 0], acc[m][n], 0, 0, 0);
      acc[m][n] = __builtin_amdgcn_mfma_f32_16x16x32_bf16(a[im * 2 + 1], bfr[n * 2 + 1], acc[m][n], 0, 0, 0);
    }
  }
}

#define FENCE asm volatile("" ::: "memory")
#define BAR do { FENCE; __builtin_amdgcn_s_barrier(); FENCE; } while (0)
#define VMW6 asm volatile("s_waitcnt vmcnt(6)" ::: "memory")
#define VMW0 asm volatile("s_waitcnt vmcnt(0)" ::: "memory")
#define PRIO1 __builtin_amdgcn_s_setprio(1)
#define PRIO0 __builtin_amdgcn_s_setprio(0)

// stage half-tile h of operand into buffer bb at K-tile kt (2 x global_load_lds 16B)
#define STG_A(bb, h, kt) do { \
    const char* g_ = Ac + aG + (unsigned)(h) * 1048576u + (unsigned)(kt) * 128u; \
    char* l_ = lds + (unsigned)(bb) * 32768u + (unsigned)(h) * 16384u + ldsT; \
    g2l16(g_, l_); g2l16(g_ + 524288u, l_ + 8192u); \
  } while (0)
#define STG_B(bb, h, kt) do { \
    const char* g_ = Bc + bG + (unsigned)(h) * 1048576u + (unsigned)(kt) * 128u; \
    char* l_ = lds + 65536u + (unsigned)(bb) * 32768u + (unsigned)(h) * 16384u + ldsT; \
    g2l16(g_, l_); g2l16(g_ + 524288u, l_ + 8192u); \
  } while (0)

#define LDA_(d, bb, m, ks) d = *(const short8*)(lds + Abase##bb + (unsigned)(m) * 2048u + frk + coff##ks)
#define LDB_(d, bb, n, ks) d = *(const short8*)(lds + Bbase##bb + (unsigned)(n) * 2048u + frk + coff##ks)

// fragment-read groups (order: A first, then B n=0,1, then B n=2,3 last so the
// compiler's lgkmcnt before P1's MFMA can leave the last 4 outstanding)
#define RD_A03(bb) do { \
    LDA_(a[0], bb, 0, 0); LDA_(a[1], bb, 0, 1); LDA_(a[2], bb, 1, 0); LDA_(a[3], bb, 1, 1); \
    LDA_(a[4], bb, 2, 0); LDA_(a[5], bb, 2, 1); LDA_(a[6], bb, 3, 0); LDA_(a[7], bb, 3, 1); \
  } while (0)
#define RD_A47(bb) do { \
    LDA_(a[0], bb, 4, 0); LDA_(a[1], bb, 4, 1); LDA_(a[2], bb, 5, 0); LDA_(a[3], bb, 5, 1); \
    LDA_(a[4], bb, 6, 0); LDA_(a[5], bb, 6, 1); LDA_(a[6], bb, 7, 0); LDA_(a[7], bb, 7, 1); \
  } while (0)
#define RD_BALL(bb) do { \
    LDB_(bfr[0], bb, 0, 0); LDB_(bfr[1], bb, 0, 1); LDB_(bfr[2], bb, 1, 0); LDB_(bfr[3], bb, 1, 1); \
    LDB_(bfr[4], bb, 2, 0); LDB_(bfr[5], bb, 2, 1); LDB_(bfr[6], bb, 3, 0); LDB_(bfr[7], bb, 3, 1); \
  } while (0)

#define MFMA_PHASE(MH, NH) do { BAR; PRIO1; mfmaq<MH, NH>(acc, a, bfr); PRIO0; BAR; } while (0)

__global__ __launch_bounds__(512, 2)
void gemm256(const bf16* __restrict__ A, const bf16* __restrict__ B,
             float* __restrict__ C, const float* __restrict__ sp) {
  extern __shared__ char lds[];

  const int tid = threadIdx.x;
  const int wave = tid >> 6, lane = tid & 63;
  const int fr = lane & 15, fq = lane >> 4;
  const int wr = wave >> 2;        // 0..1 (M)
  const int wc = wave & 3;         // 0..3 (N)

  // bijective XCD swizzle (2048 % 8 == 0)
  int wgid = blockIdx.x;
  wgid = (wgid & 7) * ((int)gridDim.x >> 3) + (wgid >> 3);
  const int bm = wgid >> 6;        // N/256 = 64 tile-cols
  const int bn = wgid & 63;

  // ---- staging addressing: thread -> (row r0, physical slot pslot) of a half-tile
  const int r0 = tid >> 3;                  // 0..63 (second load adds +64 rows)
  const int pslot = tid & 7;
  const int lslot = pslot ^ (r0 & 7);       // inverse-swizzled source slot
  const unsigned aG = ((unsigned)(bm * 256 + r0) * K_DIM + (unsigned)lslot * 8u) * 2u;
  const unsigned bG = ((unsigned)(bn * 256 + r0) * K_DIM + (unsigned)lslot * 8u) * 2u;
  const unsigned ldsT = (unsigned)tid * 16u;
  const char* Ac = (const char*)A;
  const char* Bc = (const char*)B;

  // ---- fragment read addressing (swizzled)
  const unsigned axor = (unsigned)(fr & 7) << 4;
  const unsigned coff0 = ((unsigned)(fq * 16)) ^ axor;        // ks=0 (k 0..31)
  const unsigned coff1 = ((unsigned)(64 + fq * 16)) ^ axor;   // ks=1 (k 32..63)
  const unsigned frk = (unsigned)fr * 128u;
  const unsigned Abase0 = (unsigned)(wr * 16384);
  const unsigned Abase1 = (unsigned)(32768 + wr * 16384);
  const unsigned Bhalf = (unsigned)(65536 + (wc >> 1) * 16384 + (wc & 1) * 8192);
  const unsigned Bbase0 = Bhalf;
  const unsigned Bbase1 = Bhalf + 32768u;

  f32x4 acc[8][4] = {};
  short8 a[8], bfr[8];

  // ---- prologue: t0 x4 half-tiles -> buf0; t1.{B0,B1,A0} -> buf1 (14 loads)
  STG_A(0, 0, 0); STG_A(0, 1, 0);
  STG_B(0, 0, 0); STG_B(0, 1, 0);
  STG_B(1, 0, 1); STG_B(1, 1, 1); STG_A(1, 0, 1);
  VMW6;      // t0 fully landed; t1's 3 half-tiles in flight
  BAR;

#pragma unroll 1
  for (int i = 0; i < 31; ++i) {
    const int t1 = 2 * i + 1, t2 = 2 * i + 2, t3 = 2 * i + 3;

    // ---- P1: buf0 q(0,0); read A[0-3] + ALL B; stage (t+1).A1 -> buf1
    RD_A03(0); RD_BALL(0);
    STG_A(1, 1, t1);
    MFMA_PHASE(0, 0);

    // ---- P2: q(0,1); stage (t+2).B0 -> buf0 (B-buf0 free after P1)
    STG_B(0, 0, t2);
    MFMA_PHASE(0, 1);

    // ---- P3: q(1,1); read A[4-7]; stage (t+2).B1 -> buf0
    RD_A47(0);
    STG_B(0, 1, t2);
    MFMA_PHASE(1, 1);

    // ---- P4: q(1,0); stage (t+2).A0 -> buf0 (A-buf0 free after P3); drain t+1
    STG_A(0, 0, t2);
    VMW6;
    MFMA_PHASE(1, 0);

    // ---- P5: buf1 q(0,0); read A[0-3] + ALL B; stage (t+2).A1 -> buf0
    RD_A03(1); RD_BALL(1);
    STG_A(0, 1, t2);
    MFMA_PHASE(0, 0);

    // ---- P6: q(0,1); stage (t+3).B0 -> buf1 (B-buf1 free after P5)
    STG_B(1, 0, t3);
    MFMA_PHASE(0, 1);

    // ---- P7: q(1,1); read A[4-7]; stage (t+3).B1 -> buf1
    RD_A47(1);
    STG_B(1, 1, t3);
    MFMA_PHASE(1, 1);

    // ---- P8: q(1,0); stage (t+3).A0 -> buf1 (A-buf1 free after P7); drain t+2
    STG_A(1, 0, t3);
    VMW6;
    MFMA_PHASE(1, 0);
  }

  // ---- peeled tail (i=31): tiles 62 (buf0) and 63 (buf1); no further staging
  {
    // P1: stage t63.A1 (last outstanding half-tile of t63)
    RD_A03(0); RD_BALL(0);
    STG_A(1, 1, 63);
    MFMA_PHASE(0, 0);
    // P2
    MFMA_PHASE(0, 1);
    // P3
    RD_A47(0);
    MFMA_PHASE(1, 1);
    // P4: drain everything (t63's 4 half-tiles = 8 loads outstanding)
    VMW0;
    MFMA_PHASE(1, 0);
    // P5
    RD_A03(1); RD_BALL(1);
    MFMA_PHASE(0, 0);
    // P6
    MFMA_PHASE(0, 1);
    // P7
    RD_A47(1);
    MFMA_PHASE(1, 1);
    // P8
    MFMA_PHASE(1, 0);
  }

  // ---- epilogue: C/D layout col = lane&15 (fr), row = fq*4 + j
  const float s = sp[0];
  const int crow0 = bm * 256 + wr * 128 + fq * 4;
  const int ccol0 = bn * 256 + wc * 64 + fr;
#pragma unroll
  for (int m = 0; m < 8; ++m) {
#pragma unroll
    for (int n = 0; n < 4; ++n) {
#pragma unroll
      for (int j = 0; j < 4; ++j) {
        C[(long)(crow0 + m * 16 + j) * N_DIM + (ccol0 + n * 16)] = acc[m][n][j] * s;
      }
    }
  }
}

// ---------------- fallback (ws too small): quantize/convert on the fly, 128^2 ----------------

__global__ __launch_bounds__(256)
void gemm_fly(const float* __restrict__ X, const float* __restrict__ W,
              float* __restrict__ C, const float* __restrict__ sp) {
  __shared__ alignas(16) bf16 As[128 * 32];
  __shared__ alignas(16) bf16 Bs[128 * 32];

  const int tid = threadIdx.x;
  const int wave = tid >> 6;
  const int lane = tid & 63;

  int wgid = blockIdx.x;
  wgid = (wgid & 7) * ((int)gridDim.x >> 3) + (wgid >> 3);
  const int nbn = N_DIM / 128;
  const int bm = wgid / nbn;
  const int bn = wgid % nbn;

  const float sc = sp[0];

  const int wr = (wave >> 1) * 64;
  const int wc = (wave & 1) * 64;
  const int fr = lane & 15;
  const int fq = lane >> 4;
  const char* AsB = (const char*)As;
  const char* BsB = (const char*)Bs;
  const unsigned aoff = (unsigned)((wr + fr) * 64 + fq * 16);
  const unsigned boff = (unsigned)((wc + fr) * 64 + fq * 16);

  f32x4 acc[4][4] = {};

  for (int kt = 0; kt < K_DIM; kt += 32) {
#pragma unroll
    for (int r = 0; r < 4; ++r) {
      int e = r * 1024 + tid * 4;
      int row = e >> 5;
      int k4 = e & 31;
      float4 xv = *(const float4*)(X + (long)(bm * 128 + row) * K_DIM + kt + k4);
      ushort4 xb;
      xb.x = f2bf(xv.x); xb.y = f2bf(xv.y); xb.z = f2bf(xv.z); xb.w = f2bf(xv.w);
      *(ushort4*)(As + e) = xb;
      float4 wv = *(const float4*)(W + (long)(bn * 128 + row) * K_DIM + kt + k4);
      ushort4 wb;
      wb.x = f2bf(rintf(fminf(fmaxf(wv.x / sc, -1.f), 1.f)));
      wb.y = f2bf(rintf(fminf(fmaxf(wv.y / sc, -1.f), 1.f)));
      wb.z = f2bf(rintf(fminf(fmaxf(wv.z / sc, -1.f), 1.f)));
      wb.w = f2bf(rintf(fminf(fmaxf(wv.w / sc, -1.f), 1.f)));
      *(ushort4*)(Bs + e) = wb;
    }
    __syncthreads();

    short8 a[4], b[4];
#pragma unroll
    for (int m = 0; m < 4; ++m)
      a[m] = *(const short8*)(AsB + aoff + m * (16 * 64));
#pragma unroll
    for (int n = 0; n < 4; ++n)
      b[n] = *(const short8*)(BsB + boff + n * (16 * 64));
#pragma unroll
    for (int m = 0; m < 4; ++m)
#pragma unroll
      for (int n = 0; n < 4; ++n)
        acc[m][n] = __builtin_amdgcn_mfma_f32_16x16x32_bf16(a[m], b[n], acc[m][n], 0, 0, 0);

    __syncthreads();
  }

  const long crow0 = (long)(bm * 128 + wr + fq * 4);
  const int ccol0 = bn * 128 + wc + fr;
#pragma unroll
  for (int m = 0; m < 4; ++m)
#pragma unroll
    for (int n = 0; n < 4; ++n)
#pragma unroll
      for (int j = 0; j < 4; ++j) {
        long row = crow0 + (long)(m * 16 + j);
        int col = ccol0 + n * 16;
        C[row * N_DIM + col] = acc[m][n][j] * sc;
      }
}

// ---------------- launch ----------------

extern "C" void kernel_launch(void* const* d_in, const int* in_sizes, int n_in,
                              void* d_out, int out_size, void* d_ws, size_t ws_size,
                              hipStream_t stream) {
  const float* x = (const float*)d_in[0];
  const float* w = (const float*)d_in[1];
  float* out = (float*)d_out;

  char* ws = (char*)d_ws;
  double* partials = (double*)ws;          // 2048 doubles = 16 KB
  float* sp = (float*)(ws + 16384);        // scale
  const size_t WQ_OFF = 32768;
  const size_t XB_OFF = WQ_OFF + (size_t)NELEM_W * 2;
  const size_t NEEDED = XB_OFF + (size_t)NELEM_X * 2;

  reduce_absw<<<2048, 256, 0, stream>>>((const float4*)w, partials, (int)(NELEM_W / 4));
  finalize_scale<<<1, 256, 0, stream>>>(partials, sp);

  if (ws_size >= NEEDED) {
    bf16* wq = (bf16*)(ws + WQ_OFF);
    bf16* xb = (bf16*)(ws + XB_OFF);
    quant_w<<<2048, 256, 0, stream>>>((const float4*)w, (ushort4*)wq, sp, (int)(NELEM_W / 4));
    cvt_x<<<2048, 256, 0, stream>>>((const float4*)x, (ushort4*)xb, (int)(NELEM_X / 4));

    static const int lds_bytes = 131072;
    (void)hipFuncSetAttribute((const void*)gemm256,
                              hipFuncAttributeMaxDynamicSharedMemorySize, lds_bytes);
    const int grid = (M_DIM / 256) * (N_DIM / 256); // 32 * 64 = 2048
    gemm256<<<grid, 512, lds_bytes, stream>>>(xb, wq, out, sp);
  } else {
    const int grid = (M_DIM / 128) * (N_DIM / 128);
    gemm_fly<<<grid, 256, 0, stream>>>(x, w, out, sp);
  }
}

// Round 5
// 681.103 us; speedup vs baseline: 2.2930x; 1.5533x over previous
//
#include <hip/hip_runtime.h>
#include <hip/hip_bf16.h>
#include <stdint.h>

typedef __attribute__((ext_vector_type(4))) int i32x4;

#define M_DIM 8192
#define K_DIM 4096
#define N_DIM 16384
#define NELEM_W ((long)N_DIM * (long)K_DIM) /* 67108864 */
#define NELEM_X ((long)M_DIM * (long)K_DIM) /* 33554432 */

// ---------------- helpers ----------------

__device__ __forceinline__ void g2l16(const void* g, void* l) {
  __builtin_amdgcn_global_load_lds(
      (const __attribute__((address_space(1))) unsigned int*)g,
      (__attribute__((address_space(3))) unsigned int*)l, 16, 0, 0);
}

// ---------------- scale = max(mean(|W|), 1e-8), deterministic fp64 ----------------

__global__ void reduce_absw(const float4* __restrict__ w4, double* __restrict__ partials, int n4) {
  const int tid = threadIdx.x;
  double s = 0.0;
  const int stride = gridDim.x * blockDim.x;
  for (int i = blockIdx.x * blockDim.x + tid; i < n4; i += stride) {
    float4 v = w4[i];
    s += (double)fabsf(v.x);
    s += (double)fabsf(v.y);
    s += (double)fabsf(v.z);
    s += (double)fabsf(v.w);
  }
  __shared__ double sd[256];
  sd[tid] = s;
  __syncthreads();
  for (int off = 128; off > 0; off >>= 1) {
    if (tid < off) sd[tid] += sd[tid + off];
    __syncthreads();
  }
  if (tid == 0) partials[blockIdx.x] = sd[0];
}

__global__ void finalize_scale(const double* __restrict__ partials, float* __restrict__ sp) {
  const int tid = threadIdx.x;
  double s = 0.0;
#pragma unroll
  for (int j = 0; j < 8; ++j) s += partials[tid * 8 + j];
  __shared__ double sd[256];
  sd[tid] = s;
  __syncthreads();
  for (int off = 128; off > 0; off >>= 1) {
    if (tid < off) sd[tid] += sd[tid + off];
    __syncthreads();
  }
  if (tid == 0) {
    double mean = sd[0] / (double)NELEM_W;
    float sc = (float)mean;
    if (sc < 1e-8f) sc = 1e-8f;
    sp[0] = sc;
  }
}

// ---------------- quantize W -> ternary int8 {-1,0,+1} ----------------

__global__ void quant_w_i8(const float4* __restrict__ w4, char* __restrict__ q,
                           const float* __restrict__ sp, int n4) {
  const float sc = sp[0];
  const int stride = gridDim.x * blockDim.x;
  for (int i = blockIdx.x * blockDim.x + threadIdx.x; i < n4; i += stride) {
    float4 v = w4[i];
    char4 o;
    o.x = (char)rintf(fminf(fmaxf(v.x / sc, -1.f), 1.f));
    o.y = (char)rintf(fminf(fmaxf(v.y / sc, -1.f), 1.f));
    o.z = (char)rintf(fminf(fmaxf(v.z / sc, -1.f), 1.f));
    o.w = (char)rintf(fminf(fmaxf(v.w / sc, -1.f), 1.f));
    *(char4*)(q + (long)i * 4) = o;
  }
}

// ---------------- quantize x rows -> int8 with per-row scale ----------------
// block = 256 threads handles one row of 4096 floats: absmax reduce, then quantize.

__global__ __launch_bounds__(256)
void quant_x_i8(const float* __restrict__ x, char* __restrict__ xq,
                float* __restrict__ s_row) {
  const int row = blockIdx.x;
  const int tid = threadIdx.x;
  const float4* xr = (const float4*)(x + (long)row * K_DIM);
  float4 v[4];
  float m = 0.f;
#pragma unroll
  for (int k = 0; k < 4; ++k) {
    v[k] = xr[tid + 256 * k];
    m = fmaxf(m, fmaxf(fmaxf(fabsf(v[k].x), fabsf(v[k].y)),
                       fmaxf(fabsf(v[k].z), fabsf(v[k].w))));
  }
  __shared__ float red[256];
  red[tid] = m;
  __syncthreads();
  for (int off = 128; off > 0; off >>= 1) {
    if (tid < off) red[tid] = fmaxf(red[tid], red[tid + off]);
    __syncthreads();
  }
  const float mx = red[0];
  const float inv = (mx > 0.f) ? (127.f / mx) : 0.f;
  if (tid == 0) s_row[row] = (mx > 0.f) ? (mx / 127.f) : 0.f;
  char4* out = (char4*)(xq + (long)row * K_DIM);
#pragma unroll
  for (int k = 0; k < 4; ++k) {
    char4 o;
    o.x = (char)fminf(fmaxf(rintf(v[k].x * inv), -127.f), 127.f);
    o.y = (char)fminf(fmaxf(rintf(v[k].y * inv), -127.f), 127.f);
    o.z = (char)fminf(fmaxf(rintf(v[k].z * inv), -127.f), 127.f);
    o.w = (char)fminf(fmaxf(rintf(v[k].w * inv), -127.f), 127.f);
    out[tid + 256 * k] = o;
  }
}

// ---------------- 256x256 8-phase i8 GEMM: C[M,N] = Xq[M,K] * Wq[N,K]^T ----------------
// Byte-identical LDS geometry to the r4 bf16 kernel: BK=128 i8 = 128B rows,
// A-buf 32KB x2, B-buf 32KB x2, XOR swizzle slot^(row&7), half-tile 128 rows
// (2 x g2l16/thread), deep vmcnt(6) ledger (3 half-tiles in flight), 8 waves,
// 16 x mfma_i32_16x16x64_i8 per phase. 32 K-tiles -> 16 iterations (half of r4:
// half the barriers, half the LDS reads, half the MFMA instrs for same FLOPs).
// Epilogue: out = i32 acc (exact) * s_row[row] * s_w.

template<int MH, int NH>
__device__ __forceinline__ void mfmaq(i32x4 (&acc)[8][4], const i32x4 (&a)[8], const i32x4 (&bfr)[8]) {
#pragma unroll
  for (int im = 0; im < 4; ++im) {
#pragma unroll
    for (int in = 0; in < 2; ++in) {
      const int m = MH * 4 + im, n = NH * 2 + in;
      acc[m][n] = __builtin_amdgcn_mfma_i32_16x16x64_i8(a[im * 2 + 0], bfr[n * 2 + 0], acc[m][n], 0, 0, 0);
      acc[m][n] = __builtin_amdgcn_mfma_i32_16x16x64_i8(a[im * 2 + 1], bfr[n * 2 + 1], acc[m][n], 0, 0, 0);
    }
  }
}

#define FENCE asm volatile("" ::: "memory")
#define BAR do { FENCE; __builtin_amdgcn_s_barrier(); FENCE; } while (0)
#define VMW6 asm volatile("s_waitcnt vmcnt(6)" ::: "memory")
#define VMW0 asm volatile("s_waitcnt vmcnt(0)" ::: "memory")
#define PRIO1 __builtin_amdgcn_s_setprio(1)
#define PRIO0 __builtin_amdgcn_s_setprio(0)

// stage half-tile h (128 rows) of operand into buffer bb at K-tile kt (2 x 16B loads)
#define STG_A(bb, h, kt) do { \
    const char* g_ = Ac + aG + (unsigned)(h) * 524288u + (unsigned)(kt) * 128u; \
    char* l_ = lds + (unsigned)(bb) * 32768u + (unsigned)(h) * 16384u + ldsT; \
    g2l16(g_, l_); g2l16(g_ + 262144u, l_ + 8192u); \
  } while (0)
#define STG_B(bb, h, kt) do { \
    const char* g_ = Bc + bG + (unsigned)(h) * 524288u + (unsigned)(kt) * 128u; \
    char* l_ = lds + 65536u + (unsigned)(bb) * 32768u + (unsigned)(h) * 16384u + ldsT; \
    g2l16(g_, l_); g2l16(g_ + 262144u, l_ + 8192u); \
  } while (0)

#define LDA_(d, bb, m, ks) d = *(const i32x4*)(lds + Abase##bb + (unsigned)(m) * 2048u + frk + coff##ks)
#define LDB_(d, bb, n, ks) d = *(const i32x4*)(lds + Bbase##bb + (unsigned)(n) * 2048u + frk + coff##ks)

#define RD_A03(bb) do { \
    LDA_(a[0], bb, 0, 0); LDA_(a[1], bb, 0, 1); LDA_(a[2], bb, 1, 0); LDA_(a[3], bb, 1, 1); \
    LDA_(a[4], bb, 2, 0); LDA_(a[5], bb, 2, 1); LDA_(a[6], bb, 3, 0); LDA_(a[7], bb, 3, 1); \
  } while (0)
#define RD_A47(bb) do { \
    LDA_(a[0], bb, 4, 0); LDA_(a[1], bb, 4, 1); LDA_(a[2], bb, 5, 0); LDA_(a[3], bb, 5, 1); \
    LDA_(a[4], bb, 6, 0); LDA_(a[5], bb, 6, 1); LDA_(a[6], bb, 7, 0); LDA_(a[7], bb, 7, 1); \
  } while (0)
#define RD_BALL(bb) do { \
    LDB_(bfr[0], bb, 0, 0); LDB_(bfr[1], bb, 0, 1); LDB_(bfr[2], bb, 1, 0); LDB_(bfr[3], bb, 1, 1); \
    LDB_(bfr[4], bb, 2, 0); LDB_(bfr[5], bb, 2, 1); LDB_(bfr[6], bb, 3, 0); LDB_(bfr[7], bb, 3, 1); \
  } while (0)

#define MFMA_PHASE(MH, NH) do { BAR; PRIO1; mfmaq<MH, NH>(acc, a, bfr); PRIO0; BAR; } while (0)

__global__ __launch_bounds__(512, 2)
void gemm_i8(const char* __restrict__ A, const char* __restrict__ B,
             float* __restrict__ C, const float* __restrict__ sp,
             const float* __restrict__ s_row) {
  extern __shared__ char lds[];

  const int tid = threadIdx.x;
  const int wave = tid >> 6, lane = tid & 63;
  const int fr = lane & 15, fq = lane >> 4;
  const int wr = wave >> 2;        // 0..1 (M)
  const int wc = wave & 3;         // 0..3 (N)

  // bijective XCD swizzle (2048 % 8 == 0)
  int wgid = blockIdx.x;
  wgid = (wgid & 7) * ((int)gridDim.x >> 3) + (wgid >> 3);
  const int bm = wgid >> 6;
  const int bn = wgid & 63;

  // staging: thread -> (row r0, physical 16B slot) of a 128-row half-tile (rows 128B)
  const int r0 = tid >> 3;                  // 0..63 (second load adds +64 rows)
  const int pslot = tid & 7;
  const int lslot = pslot ^ (r0 & 7);       // inverse-swizzled source slot
  const unsigned aG = (unsigned)(bm * 256 + r0) * (unsigned)K_DIM + (unsigned)lslot * 16u;
  const unsigned bG = (unsigned)(bn * 256 + r0) * (unsigned)K_DIM + (unsigned)lslot * 16u;
  const unsigned ldsT = (unsigned)tid * 16u;
  const char* Ac = A;
  const char* Bc = B;

  // fragment read addressing (swizzled); rows are 128B, ks=1 -> +64B — same bytes as r4
  const unsigned axor = (unsigned)(fr & 7) << 4;
  const unsigned coff0 = ((unsigned)(fq * 16)) ^ axor;
  const unsigned coff1 = ((unsigned)(64 + fq * 16)) ^ axor;
  const unsigned frk = (unsigned)fr * 128u;
  const unsigned Abase0 = (unsigned)(wr * 16384);
  const unsigned Abase1 = (unsigned)(32768 + wr * 16384);
  const unsigned Bhalf = (unsigned)(65536 + (wc >> 1) * 16384 + (wc & 1) * 8192);
  const unsigned Bbase0 = Bhalf;
  const unsigned Bbase1 = Bhalf + 32768u;

  i32x4 acc[8][4] = {};
  i32x4 a[8], bfr[8];

  // prologue: t0 x4 half-tiles -> buf0; t1.{B0,B1,A0} -> buf1 (14 loads)
  STG_A(0, 0, 0); STG_A(0, 1, 0);
  STG_B(0, 0, 0); STG_B(0, 1, 0);
  STG_B(1, 0, 1); STG_B(1, 1, 1); STG_A(1, 0, 1);
  VMW6;
  BAR;

#pragma unroll 1
  for (int i = 0; i < 15; ++i) {
    const int t1 = 2 * i + 1, t2 = 2 * i + 2, t3 = 2 * i + 3;

    // P1: buf0 q(0,0); read A[0-3] + ALL B; stage (t+1).A1 -> buf1
    RD_A03(0); RD_BALL(0);
    STG_A(1, 1, t1);
    MFMA_PHASE(0, 0);
    // P2: q(0,1); stage (t+2).B0 -> buf0 (B-buf0 free after P1)
    STG_B(0, 0, t2);
    MFMA_PHASE(0, 1);
    // P3: q(1,1); read A[4-7]; stage (t+2).B1 -> buf0
    RD_A47(0);
    STG_B(0, 1, t2);
    MFMA_PHASE(1, 1);
    // P4: q(1,0); stage (t+2).A0 -> buf0; drain t+1
    STG_A(0, 0, t2);
    VMW6;
    MFMA_PHASE(1, 0);
    // P5: buf1 q(0,0); read A[0-3] + ALL B; stage (t+2).A1 -> buf0
    RD_A03(1); RD_BALL(1);
    STG_A(0, 1, t2);
    MFMA_PHASE(0, 0);
    // P6: q(0,1); stage (t+3).B0 -> buf1
    STG_B(1, 0, t3);
    MFMA_PHASE(0, 1);
    // P7: q(1,1); read A[4-7]; stage (t+3).B1 -> buf1
    RD_A47(1);
    STG_B(1, 1, t3);
    MFMA_PHASE(1, 1);
    // P8: q(1,0); stage (t+3).A0 -> buf1; drain t+2
    STG_A(1, 0, t3);
    VMW6;
    MFMA_PHASE(1, 0);
  }

  // peeled tail: tiles 30 (buf0) and 31 (buf1)
  {
    RD_A03(0); RD_BALL(0);
    STG_A(1, 1, 31);           // last outstanding half-tile of t31
    MFMA_PHASE(0, 0);
    MFMA_PHASE(0, 1);
    RD_A47(0);
    MFMA_PHASE(1, 1);
    VMW0;                      // drain everything (t31 fully landed)
    MFMA_PHASE(1, 0);
    RD_A03(1); RD_BALL(1);
    MFMA_PHASE(0, 0);
    MFMA_PHASE(0, 1);
    RD_A47(1);
    MFMA_PHASE(1, 1);
    MFMA_PHASE(1, 0);
  }

  // epilogue: C/D layout col = lane&15 (fr), row = fq*4 + j; out = acc * s_row[row] * sw
  const float sw = sp[0];
  const int crow0 = bm * 256 + wr * 128 + fq * 4;
  const int ccol0 = bn * 256 + wc * 64 + fr;
#pragma unroll
  for (int m = 0; m < 8; ++m) {
#pragma unroll
    for (int j = 0; j < 4; ++j) {
      const int row = crow0 + m * 16 + j;
      const float sc = s_row[row] * sw;
#pragma unroll
      for (int n = 0; n < 4; ++n) {
        C[(long)row * N_DIM + (ccol0 + n * 16)] = (float)acc[m][n][j] * sc;
      }
    }
  }
}

// ---------------- fallback (ws too small): bf16 on-the-fly 128^2 ----------------

typedef __hip_bfloat16 bf16;
typedef __attribute__((ext_vector_type(8))) short short8;
typedef __attribute__((ext_vector_type(4))) float f32x4;

__device__ __forceinline__ unsigned short f2bf(float f) {
  unsigned int u = __float_as_uint(f);
  u += 0x7FFFu + ((u >> 16) & 1u);
  return (unsigned short)(u >> 16);
}

__global__ __launch_bounds__(256)
void gemm_fly(const float* __restrict__ X, const float* __restrict__ W,
              float* __restrict__ C, const float* __restrict__ sp) {
  __shared__ alignas(16) bf16 As[128 * 32];
  __shared__ alignas(16) bf16 Bs[128 * 32];

  const int tid = threadIdx.x;
  const int wave = tid >> 6;
  const int lane = tid & 63;

  int wgid = blockIdx.x;
  wgid = (wgid & 7) * ((int)gridDim.x >> 3) + (wgid >> 3);
  const int nbn = N_DIM / 128;
  const int bm = wgid / nbn;
  const int bn = wgid % nbn;

  const float sc = sp[0];

  const int wr = (wave >> 1) * 64;
  const int wc = (wave & 1) * 64;
  const int fr = lane & 15;
  const int fq = lane >> 4;
  const char* AsB = (const char*)As;
  const char* BsB = (const char*)Bs;
  const unsigned aoff = (unsigned)((wr + fr) * 64 + fq * 16);
  const unsigned boff = (unsigned)((wc + fr) * 64 + fq * 16);

  f32x4 acc[4][4] = {};

  for (int kt = 0; kt < K_DIM; kt += 32) {
#pragma unroll
    for (int r = 0; r < 4; ++r) {
      int e = r * 1024 + tid * 4;
      int row = e >> 5;
      int k4 = e & 31;
      float4 xv = *(const float4*)(X + (long)(bm * 128 + row) * K_DIM + kt + k4);
      ushort4 xb;
      xb.x = f2bf(xv.x); xb.y = f2bf(xv.y); xb.z = f2bf(xv.z); xb.w = f2bf(xv.w);
      *(ushort4*)(As + e) = xb;
      float4 wv = *(const float4*)(W + (long)(bn * 128 + row) * K_DIM + kt + k4);
      ushort4 wb;
      wb.x = f2bf(rintf(fminf(fmaxf(wv.x / sc, -1.f), 1.f)));
      wb.y = f2bf(rintf(fminf(fmaxf(wv.y / sc, -1.f), 1.f)));
      wb.z = f2bf(rintf(fminf(fmaxf(wv.z / sc, -1.f), 1.f)));
      wb.w = f2bf(rintf(fminf(fmaxf(wv.w / sc, -1.f), 1.f)));
      *(ushort4*)(Bs + e) = wb;
    }
    __syncthreads();

    short8 a[4], b[4];
#pragma unroll
    for (int m = 0; m < 4; ++m)
      a[m] = *(const short8*)(AsB + aoff + m * (16 * 64));
#pragma unroll
    for (int n = 0; n < 4; ++n)
      b[n] = *(const short8*)(BsB + boff + n * (16 * 64));
#pragma unroll
    for (int m = 0; m < 4; ++m)
#pragma unroll
      for (int n = 0; n < 4; ++n)
        acc[m][n] = __builtin_amdgcn_mfma_f32_16x16x32_bf16(a[m], b[n], acc[m][n], 0, 0, 0);

    __syncthreads();
  }

  const long crow0 = (long)(bm * 128 + wr + fq * 4);
  const int ccol0 = bn * 128 + wc + fr;
#pragma unroll
  for (int m = 0; m < 4; ++m)
#pragma unroll
    for (int n = 0; n < 4; ++n)
#pragma unroll
      for (int j = 0; j < 4; ++j) {
        long row = crow0 + (long)(m * 16 + j);
        int col = ccol0 + n * 16;
        C[row * N_DIM + col] = acc[m][n][j] * sc;
      }
}

// ---------------- launch ----------------

extern "C" void kernel_launch(void* const* d_in, const int* in_sizes, int n_in,
                              void* d_out, int out_size, void* d_ws, size_t ws_size,
                              hipStream_t stream) {
  const float* x = (const float*)d_in[0];
  const float* w = (const float*)d_in[1];
  float* out = (float*)d_out;

  char* ws = (char*)d_ws;
  double* partials = (double*)ws;                 // 16 KB
  float* sp = (float*)(ws + 16384);               // scale (mean|W|)
  const size_t SROW_OFF = 32768;                  // 8192 floats = 32 KB
  const size_t WQ_OFF = SROW_OFF + 32768;
  const size_t XQ_OFF = WQ_OFF + (size_t)NELEM_W; // i8
  const size_t NEEDED = XQ_OFF + (size_t)NELEM_X; // ~96 MB

  reduce_absw<<<2048, 256, 0, stream>>>((const float4*)w, partials, (int)(NELEM_W / 4));
  finalize_scale<<<1, 256, 0, stream>>>(partials, sp);

  if (ws_size >= NEEDED) {
    float* s_row = (float*)(ws + SROW_OFF);
    char* wq = ws + WQ_OFF;
    char* xq = ws + XQ_OFF;
    quant_w_i8<<<2048, 256, 0, stream>>>((const float4*)w, wq, sp, (int)(NELEM_W / 4));
    quant_x_i8<<<M_DIM, 256, 0, stream>>>(x, xq, s_row);

    static const int lds_bytes = 131072;
    (void)hipFuncSetAttribute((const void*)gemm_i8,
                              hipFuncAttributeMaxDynamicSharedMemorySize, lds_bytes);
    const int grid = (M_DIM / 256) * (N_DIM / 256); // 2048
    gemm_i8<<<grid, 512, lds_bytes, stream>>>(xq, wq, out, sp, s_row);
  } else {
    const int grid = (M_DIM / 128) * (N_DIM / 128);
    gemm_fly<<<grid, 256, 0, stream>>>(x, w, out, sp);
  }
}